// Round 1
// baseline (80.856 us; speedup 1.0000x reference)
//
#include <hip/hip_runtime.h>
#include <hip/hip_fp16.h>

// Native clang vector types: __builtin_nontemporal_* requires these
// (HIP_vector_type structs are rejected).
typedef int   vi2 __attribute__((ext_vector_type(2)));
typedef float vf2 __attribute__((ext_vector_type(2)));

// ---------------------------------------------------------------------------
// Compile-time consequent membership table (constexpr => inline literals).
// zmf[r][k] = exp(-(k-40r)^2 / 1800)
// ---------------------------------------------------------------------------
static constexpr double cexp_taylor(double x) {
    double s = 1.0, t = 1.0;
    for (int i = 1; i < 40; ++i) { t = t * x / (double)i; s += t; }
    return s;
}
static constexpr double cpow_int(double b, long e) {
    double r = 1.0, p = b;
    while (e > 0) { if (e & 1) r *= p; p *= p; e >>= 1; }
    return r;
}
struct ZmfTab { float v[5][161]; };
static constexpr ZmfTab make_zmf() {
    ZmfTab t{};
    const double c0 = cexp_taylor(-1.0 / 1800.0);
    for (int r = 0; r < 5; ++r)
        for (int k = 0; k < 161; ++k) {
            long d = (long)(k - 40 * r);
            t.v[r][k] = (float)cpow_int(c0, d * d);
        }
    return t;
}
static constexpr ZmfTab ZMF = make_zmf();
static constexpr float ZCUT = 1e-4f;

// F(x1, u): full Mamdani inference + centroid, x1 in [0,4], u = angle/45 in [0,4].
__device__ __forceinline__ float fuzzy_F(float x1, float u)
{
    float m1[5], m2[5];
#pragma unroll
    for (int i = 0; i < 5; ++i) {
        float d1 = x1 - (float)i;
        float d2 = u  - (float)i;
        m1[i] = __expf(-0.5f * d1 * d1);
        m2[i] = __expf(-0.5f * d2 * d2);
    }

    float a0 = fmaxf(fmaxf(fminf(m1[2], m2[4]), fminf(m1[3], m2[4])),
               fmaxf(fminf(m1[3], m2[3]),
               fmaxf(fminf(m1[4], m2[3]), fminf(m1[4], m2[4]))));
    float a1 = fmaxf(fmaxf(fminf(m1[1], m2[4]), fminf(m1[2], m2[3])),
               fmaxf(fminf(m1[3], m2[2]), fminf(m1[4], m2[1])));
    float a2 = fmaxf(fmaxf(fminf(m1[0], m2[4]), fminf(m1[1], m2[3])),
               fmaxf(fminf(m1[2], m2[2]),
               fmaxf(fminf(m1[3], m2[1]), fminf(m1[4], m2[0]))));
    float a3 = fmaxf(fmaxf(fminf(m1[0], m2[3]), fminf(m1[1], m2[2])),
               fmaxf(fminf(m1[2], m2[1]), fminf(m1[3], m2[0])));
    float a4 = fmaxf(fmaxf(fmaxf(fminf(m1[0], m2[2]), fminf(m1[0], m2[1])),
               fmaxf(fminf(m1[0], m2[0]), fminf(m1[1], m2[1]))),
               fmaxf(fminf(m1[1], m2[0]), fminf(m1[2], m2[0])));
    float a[5] = {a0, a1, a2, a3, a4};

    float s0 = 0.0f, s1 = 0.0f;
#pragma unroll
    for (int k = 0; k < 161; ++k) {
        float m = -1.0f;
        bool first = true;
#pragma unroll
        for (int r = 0; r < 5; ++r) {
            if (ZMF.v[r][k] >= ZCUT) {          // compile-time constant guard
                float tmin = fminf(a[r], ZMF.v[r][k]);
                m = first ? tmin : fmaxf(m, tmin);
                first = false;
            }
        }
        s0 += m;
        s1 = fmaf(m, (float)k, s1);
    }
    return fmaf(0.01f, s1 / s0, -0.3f);
}

// ---------------------------------------------------------------------------
// Table: VN x VN f32 grid over [0,4]^2 (node values, NOT patches).
// 71*71*4 B = 19.7 KB -> 4 blocks/CU x 512 threads = 32 waves/CU.
// Bilinear read = two ds_read2_b32 (offsets {0,1} and {VN,VN+1} dwords).
// ---------------------------------------------------------------------------
#define PN 70
#define VN 71
#define TAB_F  ((VN * VN + 3) & ~3)   // 5044 floats (uint4-padded)
#define TAB_U4 (TAB_F / 4)            // 1261 uint4

struct H8 { __half2 p0, p1, p2, p3; };   // one packed 16 B h-row

// Fused: blocks [0,nA) build the f32 grid table (71x71 F-evals);
// blocks [nA,...) pack h rows (8 x f32 -> 16 B fp16).
__global__ __launch_bounds__(256) void build_pack_kernel(
    const float4* __restrict__ h4, float* __restrict__ gtab,
    __half2* __restrict__ hp, int N, int nA)
{
    int b = blockIdx.x;
    if (b < nA) {
        int idx = b * 256 + threadIdx.x;
        if (idx >= VN * VN) return;
        int i = idx / VN;
        int j = idx - i * VN;
        const float hstep = 4.0f / (float)PN;
        gtab[idx] = fuzzy_F((float)i * hstep, (float)j * hstep);
    } else {
        int r = (b - nA) * 256 + threadIdx.x;
        if (r >= N) return;
        float4 a = h4[2 * r], c = h4[2 * r + 1];
        __half2* o = hp + 4 * r;
        o[0] = __floats2half2_rn(a.x, a.y);
        o[1] = __floats2half2_rn(a.z, a.w);
        o[2] = __floats2half2_rn(c.x, c.y);
        o[3] = __floats2half2_rn(c.z, c.w);
    }
}

// Per-edge: 2 scattered h-row gathers (TA) + 2 LDS reads (ds_read2_b32).
__device__ __forceinline__ float edge_eval(
    const H8* __restrict__ hp, const float* __restrict__ stab,
    int si, int di)
{
    H8 s = hp[si];
    H8 d = hp[di];

    float2 d0 = __half22float2(__hsub2(d.p0, s.p0));
    float2 d1 = __half22float2(__hsub2(d.p1, s.p1));
    float2 d2 = __half22float2(__hsub2(d.p2, s.p2));
    float2 d3 = __half22float2(__hsub2(d.p3, s.p3));

    float ss = fmaf(d0.x, d0.x, fmaf(d0.y, d0.y, fmaf(d1.x, d1.x, fmaf(d1.y, d1.y,
               fmaf(d2.x, d2.x, fmaf(d2.y, d2.y, fmaf(d3.x, d3.x,
               fmaf(d3.y, d3.y, 1e-12f))))))));

    float rn = rsqrtf(ss);
    float n  = ss * rn;                 // sqrt(ss)
    float x1 = fminf(n, 4.0f);

    float c = d0.x * rn;
    c = fminf(fmaxf(c, -0.999999f), 0.999999f);

    // Hastings acos: max err 6.7e-5 rad.
    float ac = fabsf(c);
    float t  = sqrtf(1.0f - ac);
    float p  = fmaf(fmaf(fmaf(-0.0187293f, ac, 0.0742610f), ac, -0.2121144f),
                    ac, 1.5707288f);
    float r0 = t * p;
    float acosv = (c < 0.0f) ? (3.14159265358979f - r0) : r0;
    float u = acosv * 1.27323954473516f;   // *4/pi == angle_deg / 45

    const float sc = (float)PN * 0.25f;    // 17.5
    float t1 = x1 * sc;
    float t2 = u  * sc;
    int i1 = min((int)t1, PN - 1);
    int i2 = min((int)t2, PN - 1);
    float f1 = t1 - (float)i1;
    float f2 = t2 - (float)i2;

    const float* ptab = stab + (i1 * VN + i2);
    float v00 = ptab[0];
    float v01 = ptab[1];
    float v10 = ptab[VN];
    float v11 = ptab[VN + 1];
    float lo = fmaf(f2, v01 - v00, v00);
    float hi = fmaf(f2, v11 - v10, v10);
    return fmaf(f1, hi - lo, lo);
}

__global__ __launch_bounds__(512, 8) void fuzzy_coupling_kernel(
    const H8*    __restrict__ hp,
    const int*   __restrict__ src,
    const int*   __restrict__ dst,
    const uint4* __restrict__ gtab4,
    float*       __restrict__ out,
    int E)
{
    __shared__ float stab[TAB_F];
    uint4* s4 = (uint4*)stab;
    for (int k = threadIdx.x; k < TAB_U4; k += 512) s4[k] = gtab4[k];
    __syncthreads();

    int t = blockIdx.x * 512 + threadIdx.x;
    int e0 = 2 * t;
    if (e0 >= E) return;

    if (e0 + 1 < E) {
        // Non-temporal on streaming index loads / output store: keep the
        // 12 MB stream out of L1 so h-rows keep their L1 residency.
        vi2 sp = __builtin_nontemporal_load((const vi2*)src + t);
        vi2 dp = __builtin_nontemporal_load((const vi2*)dst + t);
        float r0 = edge_eval(hp, stab, sp.x, dp.x);
        float r1 = edge_eval(hp, stab, sp.y, dp.y);
        vf2 res; res.x = r0; res.y = r1;
        __builtin_nontemporal_store(res, (vf2*)out + t);
    } else {
        out[e0] = edge_eval(hp, stab, src[e0], dst[e0]);
    }
}

extern "C" void kernel_launch(void* const* d_in, const int* in_sizes, int n_in,
                              void* d_out, int out_size, void* d_ws, size_t ws_size,
                              hipStream_t stream)
{
    const float* h   = (const float*)d_in[0];
    const int*   src = (const int*)d_in[1];
    const int*   dst = (const int*)d_in[2];
    // d_in[3] (etypes) unused by the reference computation.
    float* out = (float*)d_out;

    // ws layout: [0, ~20 KB) f32 grid table; [64 KB, 64 KB + 16*N) fp16 rows.
    float*   gtab = (float*)d_ws;
    __half2* hp   = (__half2*)((char*)d_ws + 65536);

    int N = in_sizes[0] / 8;
    int E = in_sizes[1];

    int nA = (VN * VN + 255) / 256;          // 20 table blocks
    int nB = (N + 255) / 256;                // pack blocks
    build_pack_kernel<<<nA + nB, 256, 0, stream>>>(
        (const float4*)h, gtab, hp, N, nA);

    int threads = (E + 1) / 2;
    int grid = (threads + 511) / 512;
    fuzzy_coupling_kernel<<<grid, 512, 0, stream>>>(
        (const H8*)hp, src, dst, (const uint4*)gtab, out, E);
}

// Round 2
// 79.007 us; speedup vs baseline: 1.0234x; 1.0234x over previous
//
#include <hip/hip_runtime.h>
#include <hip/hip_fp16.h>

// Native clang vector types: __builtin_nontemporal_* requires these
// (HIP_vector_type structs are rejected).
typedef int   vi4 __attribute__((ext_vector_type(4)));
typedef float vf4 __attribute__((ext_vector_type(4)));

// ---------------------------------------------------------------------------
// Compile-time consequent membership table (constexpr => inline literals).
// zmf[r][k] = exp(-(k-40r)^2 / 1800)
// ---------------------------------------------------------------------------
static constexpr double cexp_taylor(double x) {
    double s = 1.0, t = 1.0;
    for (int i = 1; i < 40; ++i) { t = t * x / (double)i; s += t; }
    return s;
}
static constexpr double cpow_int(double b, long e) {
    double r = 1.0, p = b;
    while (e > 0) { if (e & 1) r *= p; p *= p; e >>= 1; }
    return r;
}
struct ZmfTab { float v[5][161]; };
static constexpr ZmfTab make_zmf() {
    ZmfTab t{};
    const double c0 = cexp_taylor(-1.0 / 1800.0);
    for (int r = 0; r < 5; ++r)
        for (int k = 0; k < 161; ++k) {
            long d = (long)(k - 40 * r);
            t.v[r][k] = (float)cpow_int(c0, d * d);
        }
    return t;
}
static constexpr ZmfTab ZMF = make_zmf();
static constexpr float ZCUT = 1e-4f;

// F(x1, u): full Mamdani inference + centroid, x1 in [0,4], u = angle/45 in [0,4].
__device__ __forceinline__ float fuzzy_F(float x1, float u)
{
    float m1[5], m2[5];
#pragma unroll
    for (int i = 0; i < 5; ++i) {
        float d1 = x1 - (float)i;
        float d2 = u  - (float)i;
        m1[i] = __expf(-0.5f * d1 * d1);
        m2[i] = __expf(-0.5f * d2 * d2);
    }

    float a0 = fmaxf(fmaxf(fminf(m1[2], m2[4]), fminf(m1[3], m2[4])),
               fmaxf(fminf(m1[3], m2[3]),
               fmaxf(fminf(m1[4], m2[3]), fminf(m1[4], m2[4]))));
    float a1 = fmaxf(fmaxf(fminf(m1[1], m2[4]), fminf(m1[2], m2[3])),
               fmaxf(fminf(m1[3], m2[2]), fminf(m1[4], m2[1])));
    float a2 = fmaxf(fmaxf(fminf(m1[0], m2[4]), fminf(m1[1], m2[3])),
               fmaxf(fminf(m1[2], m2[2]),
               fmaxf(fminf(m1[3], m2[1]), fminf(m1[4], m2[0]))));
    float a3 = fmaxf(fmaxf(fminf(m1[0], m2[3]), fminf(m1[1], m2[2])),
               fmaxf(fminf(m1[2], m2[1]), fminf(m1[3], m2[0])));
    float a4 = fmaxf(fmaxf(fmaxf(fminf(m1[0], m2[2]), fminf(m1[0], m2[1])),
               fmaxf(fminf(m1[0], m2[0]), fminf(m1[1], m2[1]))),
               fmaxf(fminf(m1[1], m2[0]), fminf(m1[2], m2[0])));
    float a[5] = {a0, a1, a2, a3, a4};

    float s0 = 0.0f, s1 = 0.0f;
#pragma unroll
    for (int k = 0; k < 161; ++k) {
        float m = -1.0f;
        bool first = true;
#pragma unroll
        for (int r = 0; r < 5; ++r) {
            if (ZMF.v[r][k] >= ZCUT) {          // compile-time constant guard
                float tmin = fminf(a[r], ZMF.v[r][k]);
                m = first ? tmin : fmaxf(m, tmin);
                first = false;
            }
        }
        s0 += m;
        s1 = fmaf(m, (float)k, s1);
    }
    return fmaf(0.01f, s1 / s0, -0.3f);
}

// ---------------------------------------------------------------------------
// Table: PN x PN fp16 patches (v00,v01,v10,v11 = 8 B) over [0,4]^2.
// PN=70 -> 39.2 KB: 4 blocks/CU x 512 threads = 32 waves/CU (occupancy probe).
// ---------------------------------------------------------------------------
#define PN 70
#define VN 71
#define TAB_U4 ((PN * PN) / 2)       // 2450 uint4 = 39200 B

struct H8 { __half2 p0, p1, p2, p3; };   // one packed 16 B h-row

// Fused: blocks [0,nA) build the fp16 patch table (71x71 F-evals);
// blocks [nA,...) pack h rows (8 x f32 -> 16 B fp16).
__global__ __launch_bounds__(256) void build_pack_kernel(
    const float4* __restrict__ h4, __half* __restrict__ gtab,
    __half2* __restrict__ hp, int N, int nA)
{
    int b = blockIdx.x;
    if (b < nA) {
        int idx = b * 256 + threadIdx.x;
        if (idx >= VN * VN) return;
        int i = idx / VN;
        int j = idx - i * VN;
        const float hstep = 4.0f / (float)PN;
        __half f = __float2half_rn(fuzzy_F((float)i * hstep, (float)j * hstep));
        if (i < PN && j < PN) gtab[4 * (i * PN + j) + 0]           = f; // v00
        if (i < PN && j > 0)  gtab[4 * (i * PN + j - 1) + 1]       = f; // v01
        if (i > 0 && j < PN)  gtab[4 * ((i - 1) * PN + j) + 2]     = f; // v10
        if (i > 0 && j > 0)   gtab[4 * ((i - 1) * PN + j - 1) + 3] = f; // v11
    } else {
        int r = (b - nA) * 256 + threadIdx.x;
        if (r >= N) return;
        float4 a = h4[2 * r], c = h4[2 * r + 1];
        __half2* o = hp + 4 * r;
        o[0] = __floats2half2_rn(a.x, a.y);
        o[1] = __floats2half2_rn(a.z, a.w);
        o[2] = __floats2half2_rn(c.x, c.y);
        o[3] = __floats2half2_rn(c.z, c.w);
    }
}

// Per-edge: 2 scattered h-row gathers (TA) + 1 LDS patch read (DS pipe).
__device__ __forceinline__ float edge_eval(
    const H8* __restrict__ hp, const uint2* __restrict__ stab,
    int si, int di)
{
    H8 s = hp[si];
    H8 d = hp[di];

    float2 d0 = __half22float2(__hsub2(d.p0, s.p0));
    float2 d1 = __half22float2(__hsub2(d.p1, s.p1));
    float2 d2 = __half22float2(__hsub2(d.p2, s.p2));
    float2 d3 = __half22float2(__hsub2(d.p3, s.p3));

    float ss = fmaf(d0.x, d0.x, fmaf(d0.y, d0.y, fmaf(d1.x, d1.x, fmaf(d1.y, d1.y,
               fmaf(d2.x, d2.x, fmaf(d2.y, d2.y, fmaf(d3.x, d3.x,
               fmaf(d3.y, d3.y, 1e-12f))))))));

    float rn = rsqrtf(ss);
    float n  = ss * rn;                 // sqrt(ss)
    float x1 = fminf(n, 4.0f);

    float c = d0.x * rn;
    c = fminf(fmaxf(c, -0.999999f), 0.999999f);

    // Hastings acos: max err 6.7e-5 rad.
    float ac = fabsf(c);
    float t  = sqrtf(1.0f - ac);
    float p  = fmaf(fmaf(fmaf(-0.0187293f, ac, 0.0742610f), ac, -0.2121144f),
                    ac, 1.5707288f);
    float r0 = t * p;
    float acosv = (c < 0.0f) ? (3.14159265358979f - r0) : r0;
    float u = acosv * 1.27323954473516f;   // *4/pi == angle_deg / 45

    const float sc = (float)PN * 0.25f;    // 17.5
    float t1 = x1 * sc;
    float t2 = u  * sc;
    int i1 = min((int)t1, PN - 1);
    int i2 = min((int)t2, PN - 1);
    float f1 = t1 - (float)i1;
    float f2 = t2 - (float)i2;

    uint2 pk = stab[i1 * PN + i2];
    float2 lo2 = __half22float2(__builtin_bit_cast(__half2, pk.x)); // v00,v01
    float2 hi2 = __half22float2(__builtin_bit_cast(__half2, pk.y)); // v10,v11
    float lo = fmaf(f2, lo2.y - lo2.x, lo2.x);
    float hi = fmaf(f2, hi2.y - hi2.x, hi2.x);
    return fmaf(f1, hi - lo, lo);
}

__global__ __launch_bounds__(512, 8) void fuzzy_coupling_kernel(
    const H8*    __restrict__ hp,
    const int*   __restrict__ src,
    const int*   __restrict__ dst,
    const uint4* __restrict__ gtab4,
    float*       __restrict__ out,
    int E)
{
    __shared__ uint4 stab4[TAB_U4];
    for (int k = threadIdx.x; k < TAB_U4; k += 512) stab4[k] = gtab4[k];
    __syncthreads();
    const uint2* stab = (const uint2*)stab4;

    int t = blockIdx.x * 512 + threadIdx.x;
    int e0 = 4 * t;
    if (e0 >= E) return;

    if (e0 + 3 < E) {
        // Non-temporal on streaming index loads / output store: keep the
        // 12 MB stream out of L1 so h-rows keep their L1 residency.
        vi4 sp = __builtin_nontemporal_load((const vi4*)src + t);
        vi4 dp = __builtin_nontemporal_load((const vi4*)dst + t);
        float r0 = edge_eval(hp, stab, sp.x, dp.x);
        float r1 = edge_eval(hp, stab, sp.y, dp.y);
        float r2 = edge_eval(hp, stab, sp.z, dp.z);
        float r3 = edge_eval(hp, stab, sp.w, dp.w);
        vf4 res; res.x = r0; res.y = r1; res.z = r2; res.w = r3;
        __builtin_nontemporal_store(res, (vf4*)out + t);
    } else {
        for (int e = e0; e < E; ++e)
            out[e] = edge_eval(hp, stab, src[e], dst[e]);
    }
}

extern "C" void kernel_launch(void* const* d_in, const int* in_sizes, int n_in,
                              void* d_out, int out_size, void* d_ws, size_t ws_size,
                              hipStream_t stream)
{
    const float* h   = (const float*)d_in[0];
    const int*   src = (const int*)d_in[1];
    const int*   dst = (const int*)d_in[2];
    // d_in[3] (etypes) unused by the reference computation.
    float* out = (float*)d_out;

    // ws layout: [0, 39.2 KB) fp16 patch table; [64 KB, 64 KB + 16*N) fp16 rows.
    __half*  gtab = (__half*)d_ws;
    __half2* hp   = (__half2*)((char*)d_ws + 65536);

    int N = in_sizes[0] / 8;
    int E = in_sizes[1];

    int nA = (VN * VN + 255) / 256;          // 20 table blocks
    int nB = (N + 255) / 256;                // pack blocks
    build_pack_kernel<<<nA + nB, 256, 0, stream>>>(
        (const float4*)h, gtab, hp, N, nA);

    int threads = (E + 3) / 4;
    int grid = (threads + 511) / 512;
    fuzzy_coupling_kernel<<<grid, 512, 0, stream>>>(
        (const H8*)hp, src, dst, (const uint4*)gtab, out, E);
}